// Round 1
// baseline (74.655 us; speedup 1.0000x reference)
//
#include <hip/hip_runtime.h>
#include <math.h>

// Problem constants (from reference setup_inputs)
constexpr int BS = 16;
constexpr int NQ = 100;
constexpr int JD = 51;
constexpr int NA = 8;    // action classes
constexpr int NI = 10;   // identity classes
constexpr int ITILE = 10;            // i-rows per block
constexpr int NTILES = NQ / ITILE;   // 10
constexpr int BLOCK = 256;

// out[b,i,j] = -(t_j*log(p_i) + (1-t_j)*log(1-p_i))            (C_prob)
//            + sum_k |pred_joint[b,i,k] - tar_joint[b,j,k]|     (C_joint)
//            + CE(pred_action[b,i])[0] + CE(pred_identity[b,i])[0]
__global__ __launch_bounds__(BLOCK) void matcher_kernel(
    const float* __restrict__ pred_conf,    // [BS,NQ,1]
    const float* __restrict__ pred_joint,   // [BS,NQ,JD]
    const float* __restrict__ pred_action,  // [BS,NQ,NA]
    const float* __restrict__ pred_ident,   // [BS,NQ,NI]
    const float* __restrict__ tar_conf,     // [BS,NQ]
    const float* __restrict__ tar_joint,    // [BS,NQ,JD]
    float* __restrict__ out)                // [BS,NQ,NQ]
{
    const int b   = blockIdx.x;
    const int it  = blockIdx.y;
    const int i0  = it * ITILE;
    const int tid = threadIdx.x;

    __shared__ float tjs[NQ * JD];       // whole batch of target joint rows (20.4 KB)
    __shared__ float pjs[ITILE][JD];     // this tile's pred joint rows
    __shared__ float lps[ITILE];         // log(sigmoid(conf_i))
    __shared__ float l1ps[ITILE];        // log(1 - sigmoid(conf_i))
    __shared__ float rowc[ITILE];        // ce_action + ce_identity per i

    // --- cooperative, coalesced staging ---
    const float* tj_g = tar_joint + (size_t)b * NQ * JD;
    for (int idx = tid; idx < NQ * JD; idx += BLOCK) tjs[idx] = tj_g[idx];

    const float* pj_g = pred_joint + ((size_t)b * NQ + i0) * JD;
    for (int idx = tid; idx < ITILE * JD; idx += BLOCK) ((float*)pjs)[idx] = pj_g[idx];

    // --- per-i row terms (10 threads) ---
    if (tid < ITILE) {
        const int row = b * NQ + i0 + tid;
        float x  = pred_conf[row];
        // log(sigmoid(x)) = -log1p(exp(-x)); log(1-sigmoid(x)) = that - x
        float lp = -log1pf(__expf(-x));
        lps[tid]  = lp;
        l1ps[tid] = lp - x;

        const float* a = pred_action + (size_t)row * NA;
        float m = a[0];
        #pragma unroll
        for (int k = 1; k < NA; k++) m = fmaxf(m, a[k]);
        float s = 0.f;
        #pragma unroll
        for (int k = 0; k < NA; k++) s += __expf(a[k] - m);
        float cea = __logf(s) + m - a[0];

        const float* pi = pred_ident + (size_t)row * NI;
        float m2 = pi[0];
        #pragma unroll
        for (int k = 1; k < NI; k++) m2 = fmaxf(m2, pi[k]);
        float s2 = 0.f;
        #pragma unroll
        for (int k = 0; k < NI; k++) s2 += __expf(pi[k] - m2);
        float cei = __logf(s2) + m2 - pi[0];

        rowc[tid] = cea + cei;
    }
    __syncthreads();

    // --- compute: thread owns column j, half the i-tile ---
    const int j  = tid & 127;        // 0..127
    const int ih = tid >> 7;         // 0 or 1 -> which half of the i-tile
    if (j < NQ) {
        // target row into registers (LDS bank-stride 51 == conflict-free for b32)
        float tj[JD];
        #pragma unroll
        for (int k = 0; k < JD; k++) tj[k] = tjs[j * JD + k];

        const float t = tar_conf[b * NQ + j];

        float* outp = out + ((size_t)b * NQ + i0) * NQ + j;
        const int il_beg = ih * (ITILE / 2);
        #pragma unroll
        for (int il = il_beg; il < il_beg + ITILE / 2; il++) {
            float s = 0.f;
            #pragma unroll
            for (int k = 0; k < JD; k++) s += fabsf(pjs[il][k] - tj[k]);
            float cp = -(t * lps[il] + (1.f - t) * l1ps[il]);
            outp[(size_t)il * NQ] = cp + s + rowc[il];
        }
    }
}

extern "C" void kernel_launch(void* const* d_in, const int* in_sizes, int n_in,
                              void* d_out, int out_size, void* d_ws, size_t ws_size,
                              hipStream_t stream) {
    const float* pred_conf   = (const float*)d_in[0];
    const float* pred_joint  = (const float*)d_in[1];
    const float* pred_action = (const float*)d_in[2];
    const float* pred_ident  = (const float*)d_in[3];
    const float* tar_conf    = (const float*)d_in[4];
    const float* tar_joint   = (const float*)d_in[5];
    // d_in[6] (tar_action) and d_in[7] (tar_identity) are unused by the reference cost.
    float* outp = (float*)d_out;

    dim3 grid(BS, NTILES);
    matcher_kernel<<<grid, BLOCK, 0, stream>>>(
        pred_conf, pred_joint, pred_action, pred_ident, tar_conf, tar_joint, outp);
}

// Round 2
// 71.661 us; speedup vs baseline: 1.0418x; 1.0418x over previous
//
#include <hip/hip_runtime.h>
#include <math.h>

// Problem constants (from reference setup_inputs)
constexpr int BS = 16;
constexpr int NQ = 100;
constexpr int JD = 51;
constexpr int NA = 8;    // action classes
constexpr int NI = 10;   // identity classes
constexpr int ITILE = 4;             // i-rows per block
constexpr int NTILES = NQ / ITILE;   // 25
constexpr int BLOCK = 256;

// out[b,i,j] = -(t_j*log(p_i) + (1-t_j)*log(1-p_i))            (C_prob)
//            + sum_k |pred_joint[b,i,k] - tar_joint[b,j,k]|     (C_joint)
//            + CE(pred_action[b,i])[0] + CE(pred_identity[b,i])[0]
__global__ __launch_bounds__(BLOCK) void matcher_kernel(
    const float* __restrict__ pred_conf,    // [BS,NQ,1]
    const float* __restrict__ pred_joint,   // [BS,NQ,JD]
    const float* __restrict__ pred_action,  // [BS,NQ,NA]
    const float* __restrict__ pred_ident,   // [BS,NQ,NI]
    const float* __restrict__ tar_conf,     // [BS,NQ]
    const float* __restrict__ tar_joint,    // [BS,NQ,JD]
    float* __restrict__ out)                // [BS,NQ,NQ]
{
    const int b   = blockIdx.x;
    const int it  = blockIdx.y;
    const int i0  = it * ITILE;
    const int tid = threadIdx.x;

    // 20.4 KB: whole batch of target joint rows. Bank stride 51 (odd) ->
    // consecutive-j reads hit distinct banks (2-way wave64 aliasing = free).
    __shared__ __align__(16) float tjs[NQ * JD];
    __shared__ __align__(16) float pjs[ITILE * JD];
    __shared__ float lps[ITILE];         // log(sigmoid(conf_i))
    __shared__ float l1ps[ITILE];        // log(1 - sigmoid(conf_i))
    __shared__ float rowc[ITILE];        // ce_action + ce_identity per i

    // --- cooperative float4 staging (both bases are 16B-aligned:
    //     b*NQ*JD*4 = b*20400, i0*JD*4 = it*816; both multiples of 16) ---
    {
        const float4* tj4 = (const float4*)(tar_joint + (size_t)b * NQ * JD);
        float4* tjs4 = (float4*)tjs;
        #pragma unroll
        for (int idx = tid; idx < (NQ * JD) / 4; idx += BLOCK)  // 1275 vec4
            tjs4[idx] = tj4[idx];

        const float4* pj4 = (const float4*)(pred_joint + ((size_t)b * NQ + i0) * JD);
        float4* pjs4 = (float4*)pjs;
        if (tid < (ITILE * JD) / 4)                              // 51 vec4
            pjs4[tid] = pj4[tid];
    }

    // --- per-i row terms (ITILE threads) ---
    if (tid < ITILE) {
        const int row = b * NQ + i0 + tid;
        float x  = pred_conf[row];
        // log(sigmoid(x)) = -log1p(exp(-x)); log(1-sigmoid(x)) = that - x
        float lp = -log1pf(__expf(-x));
        lps[tid]  = lp;
        l1ps[tid] = lp - x;

        const float* a = pred_action + (size_t)row * NA;
        float m = a[0];
        #pragma unroll
        for (int k = 1; k < NA; k++) m = fmaxf(m, a[k]);
        float s = 0.f;
        #pragma unroll
        for (int k = 0; k < NA; k++) s += __expf(a[k] - m);
        float cea = __logf(s) + m - a[0];

        const float* pi = pred_ident + (size_t)row * NI;
        float m2 = pi[0];
        #pragma unroll
        for (int k = 1; k < NI; k++) m2 = fmaxf(m2, pi[k]);
        float s2 = 0.f;
        #pragma unroll
        for (int k = 0; k < NI; k++) s2 += __expf(pi[k] - m2);
        float cei = __logf(s2) + m2 - pi[0];

        rowc[tid] = cea + cei;
    }
    __syncthreads();

    // --- compute: thread owns column j; two waves split the i-tile ---
    const int j  = tid & 127;        // 0..127 (j<NQ active)
    const int ih = tid >> 7;         // 0 or 1 -> which half of the i-tile
    if (j < NQ) {
        // target row into registers
        float tj[JD];
        #pragma unroll
        for (int k = 0; k < JD; k++) tj[k] = tjs[j * JD + k];

        const float t = tar_conf[b * NQ + j];

        float* outp = out + ((size_t)b * NQ + i0) * NQ + j;
        const int il_beg = ih * (ITILE / 2);
        #pragma unroll
        for (int il = il_beg; il < il_beg + ITILE / 2; il++) {
            // 4-way split accumulators: break the 51-long dependent add chain
            float s0 = 0.f, s1 = 0.f, s2 = 0.f, s3 = 0.f;
            #pragma unroll
            for (int k = 0; k + 3 < JD; k += 4) {
                s0 += fabsf(pjs[il * JD + k + 0] - tj[k + 0]);
                s1 += fabsf(pjs[il * JD + k + 1] - tj[k + 1]);
                s2 += fabsf(pjs[il * JD + k + 2] - tj[k + 2]);
                s3 += fabsf(pjs[il * JD + k + 3] - tj[k + 3]);
            }
            // JD = 51: 48 handled above, 3 remain
            s0 += fabsf(pjs[il * JD + 48] - tj[48]);
            s1 += fabsf(pjs[il * JD + 49] - tj[49]);
            s2 += fabsf(pjs[il * JD + 50] - tj[50]);
            float s = (s0 + s1) + (s2 + s3);
            float cp = -(t * lps[il] + (1.f - t) * l1ps[il]);
            outp[(size_t)il * NQ] = cp + s + rowc[il];
        }
    }
}

extern "C" void kernel_launch(void* const* d_in, const int* in_sizes, int n_in,
                              void* d_out, int out_size, void* d_ws, size_t ws_size,
                              hipStream_t stream) {
    const float* pred_conf   = (const float*)d_in[0];
    const float* pred_joint  = (const float*)d_in[1];
    const float* pred_action = (const float*)d_in[2];
    const float* pred_ident  = (const float*)d_in[3];
    const float* tar_conf    = (const float*)d_in[4];
    const float* tar_joint   = (const float*)d_in[5];
    // d_in[6] (tar_action) and d_in[7] (tar_identity) are unused by the reference cost.
    float* outp = (float*)d_out;

    dim3 grid(BS, NTILES);
    matcher_kernel<<<grid, BLOCK, 0, stream>>>(
        pred_conf, pred_joint, pred_action, pred_ident, tar_conf, tar_joint, outp);
}